// Round 5
// baseline (243.480 us; speedup 1.0000x reference)
//
#include <hip/hip_runtime.h>
#include <hip/hip_bf16.h>

// Problem constants (from reference)
#define NN   2048      // B*S nodes
#define BB   16
#define SS   128
#define HH   256       // hidden
#define DE   192
#define DR   64
#define DIN  256
#define LOUT 12
#define NLEV 21
#define TE   127       // edges per tree (S-1)

#define NT   16        // trees
#define CB   16        // col-blocks per tree
#define WC   16        // columns per block
#define RB   16
#define KP   264       // padded bf16 row stride (528B rows, 16B-aligned, bank-rotating)

// Sentinel: published h is finite => 4x bf16 NaN(0xFFFF) pattern is impossible.
#define SENT64 0xFFFFFFFFFFFFFFFFULL

typedef unsigned long long ull;
typedef __attribute__((ext_vector_type(8))) short short8v;  // bf16x8 MFMA frag
typedef __attribute__((ext_vector_type(4))) float f32x4;    // MFMA accumulator

__device__ __forceinline__ float sigm(float x){ return 1.f/(1.f + __expf(-x)); }

__device__ __forceinline__ short f2bf(float f){
    union { __hip_bfloat16 b; short s; } v; v.b = __float2bfloat16(f); return v.s;
}
__device__ __forceinline__ float bf2f(short s){
    union { unsigned u; float f; } v; v.u = ((unsigned)(unsigned short)s) << 16; return v.f;
}
// relaxed agent-scope (device-coherent, cache-bypassing) accessors
__device__ __forceinline__ void st_dev(ull* p, ull v){
    __hip_atomic_store(p, v, __ATOMIC_RELAXED, __HIP_MEMORY_SCOPE_AGENT);
}
__device__ __forceinline__ ull ld_dev(const ull* p){
    return __hip_atomic_load(p, __ATOMIC_RELAXED, __HIP_MEMORY_SCOPE_AGENT);
}
__device__ __forceinline__ void st_devf(float* p, float v){
    __hip_atomic_store(p, v, __ATOMIC_RELAXED, __HIP_MEMORY_SCOPE_AGENT);
}
__device__ __forceinline__ int ld_devi(const int* p){
    return __hip_atomic_load(p, __ATOMIC_RELAXED, __HIP_MEMORY_SCOPE_AGENT);
}

// Pack 4 cols (bf16) from 4 adjacent lanes, store 1 ull (lanes with cc%4==0).
__device__ __forceinline__ void publish4(float hv, int cc, ull* rowp, int col0){
    unsigned p = (unsigned short)f2bf(hv);
    unsigned q = (unsigned)__shfl_xor((int)p, 1);
    unsigned pr = p | (q << 16);
    unsigned pr2 = (unsigned)__shfl_xor((int)pr, 2);
    if ((cc & 3) == 0)
        st_dev(rowp + ((col0 + cc) >> 2), pr | ((ull)pr2 << 32));
}

// ---------------------------------------------------------------------------
// Sentinel pre-fill (race-free: completes before tree_k starts, stream order)
// ---------------------------------------------------------------------------
__global__ __launch_bounds__(256) void fill_k(ull* __restrict__ hx,
                                              int* __restrict__ pb)
{
    const int t = threadIdx.x;
    const size_t base = (size_t)blockIdx.x * 512 + t;
    st_dev(&hx[base], SENT64);
    st_dev(&hx[base + 256], SENT64);
    if (blockIdx.x == 0) {
        #pragma unroll
        for (int q = 0; q < (BB*HH)/256; ++q)
            __hip_atomic_store(&pb[q*256 + t], -1, __ATOMIC_RELAXED,
                               __HIP_MEMORY_SCOPE_AGENT);
    }
}

// ---------------------------------------------------------------------------
// Fully-async wave-autonomous dataflow recurrence: ZERO barriers in the
// recurrence. All 128 nodes (leaves included) form one height-sorted queue;
// wave w owns queue positions == w (mod 4) and free-runs. Waits occur only on
// true data deps (global h sentinel polls). Producer fences cloc/hloc LDS
// writes with lgkmcnt(0) BEFORE publishing to hx, so a consumer that sees the
// own-block hx slice also sees cloc. Deadlock-free: a node's children are
// strictly earlier in every block's identical queue.
// ---------------------------------------------------------------------------
__global__ __launch_bounds__(256, 1) void tree_k(
    const int* __restrict__ xs, const int* __restrict__ rels,
    const float* __restrict__ emb_W, const float* __restrict__ rel_W,
    const float* __restrict__ W_ix, const float* __restrict__ b_ix,
    const float* __restrict__ W_fx, const float* __restrict__ b_fx,
    const float* __restrict__ W_ox, const float* __restrict__ W_ux,
    const int* __restrict__ child_idx, const int* __restrict__ parent_idx,
    const int* __restrict__ node_height,
    const float* __restrict__ W_ih, const float* __restrict__ b_ih,
    const float* __restrict__ W_fh, const float* __restrict__ b_fh,
    const float* __restrict__ W_oh, const float* __restrict__ W_uh,
    ull* __restrict__ hx, float* __restrict__ poolbuf,
    const float* __restrict__ W_out, const float* __restrict__ b_out,
    float* __restrict__ out)
{
    // ---- dynamic LDS (67584 B) ----
    extern __shared__ __align__(16) char trans[];
    short* Wbf    = (short*)trans;                  // [4][WC][KP] recurrent W, col-major
    short* hstage = (short*)(trans + 4*WC*KP*2);    // [4 waves][16 rows][KP]; prologue xbf

    // ---- static LDS ----
    __shared__ float projL[4][SS][WC];       // {ix,fx,ox,ux} own-col slices
    __shared__ float cloc[SS][WC+1];
    __shared__ float hloc[SS][WC+1];
    __shared__ short hsrow[4][KP];           // per-wave hsum row (bf16)
    __shared__ float biasF[WC], biasI[WC];
    __shared__ int loff[SS+1], lcur[SS], llist[SS];
    __shared__ int lvoff[NLEV+1], lvcur[NLEV], lvnodes[SS];
    __shared__ int s_maxH;

    const int t    = threadIdx.x;
    const int bid  = blockIdx.x;
    const int xcd  = bid & 7;                // XCD-affine (perf only)
    const int idx  = bid >> 3;
    const int b    = xcd + 8 * (idx >> 4);   // tree
    const int cgp  = idx & 15;               // col group
    const int col0 = cgp * WC;
    const int cc   = t & 15;
    const int rr   = t >> 4;
    const int wv   = t >> 6;                 // wave id
    const int lane = t & 63;
    const int col  = lane & 15;              // MFMA col / A-row index
    const int kg   = lane >> 4;              // MFMA k-slot group

    // ---- P0: stage xs/rels ints; zero counters ----
    if (t < SS) { llist[t] = xs[b*SS + t]; lvnodes[t] = rels[b*SS + t]; lcur[t] = 0; }
    if (t < NLEV) lvcur[t] = 0;
    if (t == 0)   s_maxH = 0;
    __syncthreads();

    // ---- CSR degree atomics + recurrent-W LDS staging + biases + W_x frags ----
    if (t < TE) { int p = parent_idx[b*TE + t] - b*SS; atomicAdd(&lcur[p], 1); }
    if (t < SS) { int hg = node_height[b*SS + t]; atomicAdd(&lvcur[hg], 1); atomicMax(&s_maxH, hg); }
    {
        const float* Wm4[4] = { W_fh, W_ih, W_oh, W_uh };
        for (int m = 0; m < 4; ++m) {
            short* dst = Wbf + (m*WC + cc)*KP;
            const float* src = Wm4[m] + col0 + cc;
            #pragma unroll 4
            for (int kb = 0; kb < 16; ++kb) {
                int k = kb*16 + rr;
                dst[k] = f2bf(src[(long long)k*HH]);
            }
        }
        if (t < WC) { biasF[t] = b_fh[col0+t]; biasI[t] = b_ih[col0+t]; }
    }
    // W_x B-frags in registers (wave wv owns gate wv)
    short8v bfr[8];
    {
        const float* Wxm = (wv==0) ? W_ix : (wv==1) ? W_fx : (wv==2) ? W_ox : W_ux;
        #pragma unroll
        for (int f = 0; f < 8; ++f) {
            #pragma unroll
            for (int j = 0; j < 8; ++j)
                bfr[f][j] = f2bf(Wxm[(long long)(f*32 + kg*8 + j)*HH + col0 + col]);
        }
    }
    const float pbias = (wv==0) ? b_ix[col0+col] : (wv==1) ? b_fx[col0+col] : 0.f;

    // ---- x-gather + proj MFMA in two 64-row halves (xbf overlays hstage) ----
    short* xbf = hstage;   // [64][KP]
    for (int half = 0; half < 2; ++half) {
        __syncthreads();
        #pragma unroll
        for (int r2 = 0; r2 < 16; ++r2) {
            int gr = half*64 + wv*16 + r2;     // global row (node index in tree)
            float4 v;
            if (lane < 48) v = *(const float4*)&emb_W[(long long)llist[gr]*DE + lane*4];
            else           v = *(const float4*)&rel_W[(long long)lvnodes[gr]*DR + (lane-48)*4];
            union { short s[4]; ull u; } pk;
            pk.s[0] = f2bf(v.x); pk.s[1] = f2bf(v.y);
            pk.s[2] = f2bf(v.z); pk.s[3] = f2bf(v.w);
            *(ull*)&xbf[(wv*16 + r2)*KP + lane*4] = pk.u;
        }
        __syncthreads();
        for (int lch = 0; lch < 4; ++lch) {
            f32x4 acc = {0.f,0.f,0.f,0.f};
            const short* ap = xbf + (lch*16 + col)*KP + kg*8;
            #pragma unroll
            for (int f = 0; f < 8; ++f)
                acc = __builtin_amdgcn_mfma_f32_16x16x32_bf16(
                    *(const short8v*)(ap + f*32), bfr[f], acc, 0,0,0);
            #pragma unroll
            for (int r = 0; r < 4; ++r)
                projL[wv][half*64 + lch*16 + kg*4 + r][col] = acc[r] + pbias;
        }
    }
    __syncthreads();

    // ---- recurrent-W register fragments (read once from Wbf) ----
    short8v wfrF[8], wfrI[8], wfrO[8], wfrU[8];
    #pragma unroll
    for (int f = 0; f < 8; ++f) {
        const int o = col*KP + f*32 + kg*8;
        wfrF[f] = *(const short8v*)(Wbf + (0*WC)*KP + o);
        wfrI[f] = *(const short8v*)(Wbf + (1*WC)*KP + o);
        wfrO[f] = *(const short8v*)(Wbf + (2*WC)*KP + o);
        wfrU[f] = *(const short8v*)(Wbf + (3*WC)*KP + o);
    }

    // ---- CSR prefix sums + scatter ----
    if (t == 0) {
        int off = 0;
        for (int i = 0; i < SS; ++i) { int v = lcur[i]; loff[i] = off; lcur[i] = off; off += v; }
        loff[SS] = off;
        off = 0;
        for (int l2 = 0; l2 < NLEV; ++l2) { int v = lvcur[l2]; lvoff[l2] = off; lvcur[l2] = off; off += v; }
        lvoff[NLEV] = off;
    }
    __syncthreads();
    if (t < TE) {
        int e = b*TE + t;
        int p = parent_idx[e] - b*SS;
        int pos = atomicAdd(&lcur[p], 1);
        llist[pos] = child_idx[e] - b*SS;
    }
    if (t < SS) {
        int hg = node_height[b*SS + t];
        int pos = atomicAdd(&lvcur[hg], 1);
        lvnodes[pos] = t;
    }
    __syncthreads();

    // ---- fully-async unified node queue (height-sorted), NO barriers ----
    short* Hst = hstage + wv*16*KP;          // this wave's staging [16][KP]
    {
        int j = wv;
        ull u[16]; int chr[4];
        int nOff = 0, nE = 0;
        {   // issue polls for first assigned node
            int n0 = lvnodes[j]; nOff = loff[n0]; nE = loff[n0+1] - nOff;
            int m0 = min(nE, 16);
            #pragma unroll
            for (int rw = 0; rw < 4; ++rw) {
                int e = kg + rw*4;
                chr[rw] = (e < m0) ? llist[nOff + e] : -1;
                if (chr[rw] >= 0) {
                    const ull* sp = hx + (size_t)(b*SS + chr[rw])*64 + col*4;
                    #pragma unroll
                    for (int q = 0; q < 4; ++q) u[rw*4+q] = ld_dev(sp+q);
                }
            }
        }
        while (j < SS) {
            const int n = lvnodes[j];
            const int off = nOff, E = nE;
            float hs0=0.f, hs1=0.f, hs2=0.f, hs3=0.f, fpart=0.f;

            if (E > 0) {
                for (int fr = 0; fr < E; fr += 16) {
                    const int m = min(16, E - fr);
                    if (fr > 0) {             // issue this frame (rare E>16)
                        #pragma unroll
                        for (int rw = 0; rw < 4; ++rw) {
                            int e = kg + rw*4;
                            chr[rw] = (e < m) ? llist[off + fr + e] : -1;
                            if (chr[rw] >= 0) {
                                const ull* sp = hx + (size_t)(b*SS + chr[rw])*64 + col*4;
                                #pragma unroll
                                for (int q = 0; q < 4; ++q) u[rw*4+q] = ld_dev(sp+q);
                            }
                        }
                    }
                    // commit: poll sentinels
                    for (;;) {
                        bool bad = false;
                        #pragma unroll
                        for (int rw = 0; rw < 4; ++rw)
                            if (chr[rw] >= 0) {
                                #pragma unroll
                                for (int q = 0; q < 4; ++q)
                                    bad = bad || (u[rw*4+q] == SENT64);
                            }
                        if (!bad) break;
                        __builtin_amdgcn_s_sleep(1);
                        #pragma unroll
                        for (int rw = 0; rw < 4; ++rw)
                            if (chr[rw] >= 0) {
                                const ull* sp = hx + (size_t)(b*SS + chr[rw])*64 + col*4;
                                #pragma unroll
                                for (int q = 0; q < 4; ++q)
                                    if (u[rw*4+q] == SENT64) u[rw*4+q] = ld_dev(sp+q);
                            }
                    }
                    // stage into LDS
                    #pragma unroll
                    for (int rw = 0; rw < 4; ++rw)
                        if (chr[rw] >= 0) {
                            int e = kg + rw*4;
                            ull* dp = (ull*)&Hst[e*KP + col*16];
                            dp[0]=u[rw*4]; dp[1]=u[rw*4+1]; dp[2]=u[rw*4+2]; dp[3]=u[rw*4+3];
                        }
                    // f-MFMA over frame edges
                    f32x4 fa = {0.f,0.f,0.f,0.f};
                    {
                        const int ro = col*KP + kg*8;
                        #pragma unroll
                        for (int f = 0; f < 8; ++f)
                            fa = __builtin_amdgcn_mfma_f32_16x16x32_bf16(
                                *(const short8v*)(Hst + ro + f*32), wfrF[f], fa, 0,0,0);
                    }
                    // fc partial (D row = kg*4+r = frame edge); cloc gated by
                    // the sentinel poll + producer-side lgkmcnt fence
                    #pragma unroll
                    for (int r = 0; r < 4; ++r) {
                        int e = kg*4 + r;
                        if (e < m) {
                            int ch2 = llist[off + fr + e];
                            float fg = sigm(fa[r] + biasF[col] + projL[1][n][col]);
                            fpart += fg * cloc[ch2][col];
                        }
                    }
                    // hsum accumulate: lane sums its 4 cols over frame edges
                    for (int e = 0; e < m; ++e) {
                        union { short s[4]; ull v; } rv;
                        rv.v = *(const ull*)&Hst[e*KP + lane*4];
                        hs0 += bf2f(rv.s[0]); hs1 += bf2f(rv.s[1]);
                        hs2 += bf2f(rv.s[2]); hs3 += bf2f(rv.s[3]);
                    }
                }
            }

            // prefetch next assigned node's child rows (hide poll flight)
            int jn = j + 4;
            if (jn < SS) {
                int n1 = lvnodes[jn]; nOff = loff[n1]; nE = loff[n1+1] - nOff;
                int m1 = min(nE, 16);
                #pragma unroll
                for (int rw = 0; rw < 4; ++rw) {
                    int e = kg + rw*4;
                    chr[rw] = (e < m1) ? llist[nOff + e] : -1;
                    if (chr[rw] >= 0) {
                        const ull* sp = hx + (size_t)(b*SS + chr[rw])*64 + col*4;
                        #pragma unroll
                        for (int q = 0; q < 4; ++q) u[rw*4+q] = ld_dev(sp+q);
                    }
                }
            }

            float dI = 0.f, dO = 0.f, dU = 0.f;
            if (E > 0) {
                // hsum row (bf16) -> iou MFMAs with shared A-frags
                {
                    union { short s[4]; ull v; } hp;
                    hp.s[0]=f2bf(hs0); hp.s[1]=f2bf(hs1);
                    hp.s[2]=f2bf(hs2); hp.s[3]=f2bf(hs3);
                    *(ull*)&hsrow[wv][lane*4] = hp.v;
                }
                f32x4 ia={0.f,0.f,0.f,0.f}, oa={0.f,0.f,0.f,0.f}, ua={0.f,0.f,0.f,0.f};
                {
                    const short* H = &hsrow[wv][0];
                    #pragma unroll
                    for (int f = 0; f < 8; ++f) {
                        short8v af = *(const short8v*)(H + f*32 + kg*8);
                        ia = __builtin_amdgcn_mfma_f32_16x16x32_bf16(af, wfrI[f], ia, 0,0,0);
                        oa = __builtin_amdgcn_mfma_f32_16x16x32_bf16(af, wfrO[f], oa, 0,0,0);
                        ua = __builtin_amdgcn_mfma_f32_16x16x32_bf16(af, wfrU[f], ua, 0,0,0);
                    }
                }
                dI = ia[0]; dO = oa[0]; dU = ua[0];
                fpart += __shfl_xor(fpart, 16);
                fpart += __shfl_xor(fpart, 32);
            }

            float hv = 0.f;
            if (lane < 16) {
                float iv = sigm(projL[0][n][lane] + dI + biasI[lane]);
                float ov = sigm(projL[2][n][lane] + dO);
                float uv = tanhf(projL[3][n][lane] + dU);
                float cv = iv*uv + fpart;
                hv = ov * tanhf(cv);
                cloc[n][lane] = cv; hloc[n][lane] = hv;
            }
            // producer fence: cloc/hloc visible BEFORE hx publish
            __builtin_amdgcn_sched_barrier(0);
            asm volatile("s_waitcnt lgkmcnt(0)" ::: "memory");
            __builtin_amdgcn_sched_barrier(0);
            if (lane < 16)
                publish4(hv, lane, hx + (size_t)(b*SS + n)*64, col0);
            j = jn;
        }
    }
    __syncthreads();   // all waves done: hloc complete for pool

    // ---- max-pool own columns, exchange via sentinel poolbuf ----
    {
        float* pp = (float*)hstage;          // [16][17] scratch (recurrence done)
        float mx = -3.4e38f;
        for (int s2 = rr; s2 < SS; s2 += RB)
            mx = fmaxf(mx, hloc[s2][cc]);
        pp[rr*17 + cc] = mx;
        __syncthreads();
        if (t < WC) {
            float m2 = pp[0*17 + t];
            #pragma unroll
            for (int r2 = 1; r2 < RB; ++r2) m2 = fmaxf(m2, pp[r2*17 + t]);
            st_devf(&poolbuf[b*HH + col0 + t], m2);
        }
    }
    if (cgp == 0) {
        const int* pb = (const int*)poolbuf + b*HH + t;
        int w = ld_devi(pb);
        while (w == -1) { __builtin_amdgcn_s_sleep(1); w = ld_devi(pb); }
        float* pl = (float*)&hsrow[0][0];    // 256 floats
        pl[t] = __int_as_float(w);
        __syncthreads();
        if (t < LOUT) {
            float acc = b_out[t];
            for (int k = 0; k < HH; ++k)
                acc += pl[k] * W_out[k*LOUT + t];
            out[b*LOUT + t] = acc;
        }
    }
}

// ---------------------------------------------------------------------------
extern "C" void kernel_launch(void* const* d_in, const int* in_sizes, int n_in,
                              void* d_out, int out_size, void* d_ws, size_t ws_size,
                              hipStream_t stream)
{
    const int* xs          = (const int*)d_in[0];
    const int* rels        = (const int*)d_in[1];
    const int* child_idx   = (const int*)d_in[2];
    const int* parent_idx  = (const int*)d_in[3];
    const int* node_height = (const int*)d_in[4];
    // d_in[5] = n_levels (hardcoded NLEV)
    const float* emb_W = (const float*)d_in[6];
    const float* rel_W = (const float*)d_in[7];
    const float* W_ix  = (const float*)d_in[8];
    const float* b_ix  = (const float*)d_in[9];
    const float* W_ih  = (const float*)d_in[10];
    const float* b_ih  = (const float*)d_in[11];
    const float* W_fx  = (const float*)d_in[12];
    const float* b_fx  = (const float*)d_in[13];
    const float* W_fh  = (const float*)d_in[14];
    const float* b_fh  = (const float*)d_in[15];
    const float* W_ox  = (const float*)d_in[16];
    const float* W_oh  = (const float*)d_in[17];
    const float* W_ux  = (const float*)d_in[18];
    const float* W_uh  = (const float*)d_in[19];
    const float* W_out = (const float*)d_in[20];
    const float* b_out = (const float*)d_in[21];

    ull*   hx      = (ull*)d_ws;                              // NN*64 ull = 1 MB
    float* poolbuf = (float*)((char*)d_ws + (size_t)NN*64*8); // BB*HH floats

    fill_k<<<256, 256, 0, stream>>>(hx, (int*)poolbuf);

    const unsigned int shmem = (unsigned int)(8u * WC * KP * 2);   // 67584 B
    tree_k<<<dim3(NT*CB), dim3(256), shmem, stream>>>(
        xs, rels, emb_W, rel_W,
        W_ix, b_ix, W_fx, b_fx, W_ox, W_ux,
        child_idx, parent_idx, node_height,
        W_ih, b_ih, W_fh, b_fh, W_oh, W_uh,
        hx, poolbuf,
        W_out, b_out, (float*)d_out);
}

// Round 6
// 233.641 us; speedup vs baseline: 1.0421x; 1.0421x over previous
//
#include <hip/hip_runtime.h>
#include <hip/hip_bf16.h>

// Problem constants (from reference)
#define NN   2048      // B*S nodes
#define BB   16
#define SS   128
#define HH   256       // hidden
#define DE   192
#define DR   64
#define DIN  256
#define LOUT 12
#define NLEV 21
#define TE   127       // edges per tree (S-1)

#define NT   16        // trees
#define CB   16        // col-blocks per tree
#define WC   16        // columns per block
#define RB   16
#define KP   264       // padded bf16 row stride (528B rows, 16B-aligned, bank-rotating)

// Sentinel: published h is finite => 4x bf16 NaN(0xFFFF) pattern is impossible.
#define SENT64 0xFFFFFFFFFFFFFFFFULL
#define FLAGS_ALL 0x0101010101010101ULL

typedef unsigned long long ull;
typedef __attribute__((ext_vector_type(8))) short short8v;  // bf16x8 MFMA frag
typedef __attribute__((ext_vector_type(4))) float f32x4;    // MFMA accumulator

__device__ __forceinline__ float sigm(float x){ return 1.f/(1.f + __expf(-x)); }

__device__ __forceinline__ short f2bf(float f){
    union { __hip_bfloat16 b; short s; } v; v.b = __float2bfloat16(f); return v.s;
}
__device__ __forceinline__ float bf2f(short s){
    union { unsigned u; float f; } v; v.u = ((unsigned)(unsigned short)s) << 16; return v.f;
}
// relaxed agent-scope (device-coherent, cache-bypassing) accessors
__device__ __forceinline__ void st_dev(ull* p, ull v){
    __hip_atomic_store(p, v, __ATOMIC_RELAXED, __HIP_MEMORY_SCOPE_AGENT);
}
__device__ __forceinline__ ull ld_dev(const ull* p){
    return __hip_atomic_load(p, __ATOMIC_RELAXED, __HIP_MEMORY_SCOPE_AGENT);
}
__device__ __forceinline__ void st_devf(float* p, float v){
    __hip_atomic_store(p, v, __ATOMIC_RELAXED, __HIP_MEMORY_SCOPE_AGENT);
}
__device__ __forceinline__ int ld_devi(const int* p){
    return __hip_atomic_load(p, __ATOMIC_RELAXED, __HIP_MEMORY_SCOPE_AGENT);
}
__device__ __forceinline__ void st_devb(unsigned char* p, unsigned char v){
    __hip_atomic_store(p, v, __ATOMIC_RELAXED, __HIP_MEMORY_SCOPE_AGENT);
}

// LDS-only barrier: waits DS ops but NOT in-flight global publish stores.
__device__ __forceinline__ void barrier_lds(){
    __builtin_amdgcn_sched_barrier(0);
    asm volatile("s_waitcnt lgkmcnt(0)" ::: "memory");
    __builtin_amdgcn_s_barrier();
    __builtin_amdgcn_sched_barrier(0);
}

// Pack 4 cols (bf16) from 4 adjacent lanes, store 1 ull (lanes with cc%4==0).
__device__ __forceinline__ void publish4(float hv, int cc, ull* rowp, int col0){
    unsigned p = (unsigned short)f2bf(hv);
    unsigned q = (unsigned)__shfl_xor((int)p, 1);
    unsigned pr = p | (q << 16);
    unsigned pr2 = (unsigned)__shfl_xor((int)pr, 2);
    if ((cc & 3) == 0)
        st_dev(rowp + ((col0 + cc) >> 2), pr | ((ull)pr2 << 32));
}

// ---------------------------------------------------------------------------
// Sentinel + flag pre-fill (race-free: stream-ordered before tree_k)
// ---------------------------------------------------------------------------
__global__ __launch_bounds__(256) void fill_k(ull* __restrict__ hx,
                                              ull* __restrict__ flg,
                                              int* __restrict__ pb)
{
    const int t = threadIdx.x;
    const size_t base = (size_t)blockIdx.x * 512 + t;
    st_dev(&hx[base], SENT64);
    st_dev(&hx[base + 256], SENT64);
    if (t < 16) st_dev(&flg[(size_t)blockIdx.x * 16 + t], 0ULL);
    if (blockIdx.x == 0) {
        #pragma unroll
        for (int q = 0; q < (BB*HH)/256; ++q)
            __hip_atomic_store(&pb[q*256 + t], -1, __ATOMIC_RELAXED,
                               __HIP_MEMORY_SCOPE_AGENT);
    }
}

// ---------------------------------------------------------------------------
// Wave-autonomous fence-free dataflow recurrence (R4 structure) with
// flag-gated retry: producers store a per-(node,colblock) ready byte after
// the data stores (no drain); consumers' slow path polls the 16B flag block
// (coalesced, ~256B/wave/retry) instead of re-loading 2KB of row data.
// Fast path (data ready at first check) is unchanged.
// ---------------------------------------------------------------------------
__global__ __launch_bounds__(256, 1) void tree_k(
    const int* __restrict__ xs, const int* __restrict__ rels,
    const float* __restrict__ emb_W, const float* __restrict__ rel_W,
    const float* __restrict__ W_ix, const float* __restrict__ b_ix,
    const float* __restrict__ W_fx, const float* __restrict__ b_fx,
    const float* __restrict__ W_ox, const float* __restrict__ W_ux,
    const int* __restrict__ child_idx, const int* __restrict__ parent_idx,
    const int* __restrict__ node_height,
    const float* __restrict__ W_ih, const float* __restrict__ b_ih,
    const float* __restrict__ W_fh, const float* __restrict__ b_fh,
    const float* __restrict__ W_oh, const float* __restrict__ W_uh,
    ull* __restrict__ hx, ull* __restrict__ flg, float* __restrict__ poolbuf,
    const float* __restrict__ W_out, const float* __restrict__ b_out,
    float* __restrict__ out)
{
    // ---- dynamic LDS (67584 B) ----
    extern __shared__ __align__(16) char trans[];
    short* Wbf    = (short*)trans;                  // [4][WC][KP] recurrent W, col-major
    short* hstage = (short*)(trans + 4*WC*KP*2);    // [4 waves][16 rows][KP]; prologue xbf

    // ---- static LDS ----
    __shared__ float projL[4][SS][WC];       // {ix,fx,ox,ux} own-col slices
    __shared__ float cloc[SS][WC+1];
    __shared__ float hloc[SS][WC+1];
    __shared__ short hsrow[4][KP];           // per-wave hsum row (bf16)
    __shared__ float biasF[WC], biasI[WC];
    __shared__ int loff[SS+1], lcur[SS], llist[SS];
    __shared__ int lvoff[NLEV+1], lvcur[NLEV], lvnodes[SS];
    __shared__ int s_maxH;

    const int t    = threadIdx.x;
    const int bid  = blockIdx.x;
    const int xcd  = bid & 7;                // XCD-affine (perf only)
    const int idx  = bid >> 3;
    const int b    = xcd + 8 * (idx >> 4);   // tree
    const int cgp  = idx & 15;               // col group
    const int col0 = cgp * WC;
    const int cc   = t & 15;
    const int rr   = t >> 4;
    const int wv   = t >> 6;                 // wave id
    const int lane = t & 63;
    const int col  = lane & 15;              // MFMA col / A-row index
    const int kg   = lane >> 4;              // MFMA k-slot group

    // ---- P0: stage xs/rels ints; zero counters ----
    if (t < SS) { llist[t] = xs[b*SS + t]; lvnodes[t] = rels[b*SS + t]; lcur[t] = 0; }
    if (t < NLEV) lvcur[t] = 0;
    if (t == 0)   s_maxH = 0;
    __syncthreads();

    // ---- CSR degree atomics + recurrent-W LDS staging + biases + W_x frags ----
    if (t < TE) { int p = parent_idx[b*TE + t] - b*SS; atomicAdd(&lcur[p], 1); }
    if (t < SS) { int hg = node_height[b*SS + t]; atomicAdd(&lvcur[hg], 1); atomicMax(&s_maxH, hg); }
    {
        const float* Wm4[4] = { W_fh, W_ih, W_oh, W_uh };
        for (int m = 0; m < 4; ++m) {
            short* dst = Wbf + (m*WC + cc)*KP;
            const float* src = Wm4[m] + col0 + cc;
            #pragma unroll 4
            for (int kb = 0; kb < 16; ++kb) {
                int k = kb*16 + rr;
                dst[k] = f2bf(src[(long long)k*HH]);
            }
        }
        if (t < WC) { biasF[t] = b_fh[col0+t]; biasI[t] = b_ih[col0+t]; }
    }
    // W_x B-frags in registers (wave wv owns gate wv)
    short8v bfr[8];
    {
        const float* Wxm = (wv==0) ? W_ix : (wv==1) ? W_fx : (wv==2) ? W_ox : W_ux;
        #pragma unroll
        for (int f = 0; f < 8; ++f) {
            #pragma unroll
            for (int j = 0; j < 8; ++j)
                bfr[f][j] = f2bf(Wxm[(long long)(f*32 + kg*8 + j)*HH + col0 + col]);
        }
    }
    const float pbias = (wv==0) ? b_ix[col0+col] : (wv==1) ? b_fx[col0+col] : 0.f;

    // ---- x-gather + proj MFMA in two 64-row halves (xbf overlays hstage) ----
    short* xbf = hstage;   // [64][KP]
    for (int half = 0; half < 2; ++half) {
        __syncthreads();
        #pragma unroll
        for (int r2 = 0; r2 < 16; ++r2) {
            int gr = half*64 + wv*16 + r2;     // global row (node index in tree)
            float4 v;
            if (lane < 48) v = *(const float4*)&emb_W[(long long)llist[gr]*DE + lane*4];
            else           v = *(const float4*)&rel_W[(long long)lvnodes[gr]*DR + (lane-48)*4];
            union { short s[4]; ull u; } pk;
            pk.s[0] = f2bf(v.x); pk.s[1] = f2bf(v.y);
            pk.s[2] = f2bf(v.z); pk.s[3] = f2bf(v.w);
            *(ull*)&xbf[(wv*16 + r2)*KP + lane*4] = pk.u;
        }
        __syncthreads();
        for (int lch = 0; lch < 4; ++lch) {
            f32x4 acc = {0.f,0.f,0.f,0.f};
            const short* ap = xbf + (lch*16 + col)*KP + kg*8;
            #pragma unroll
            for (int f = 0; f < 8; ++f)
                acc = __builtin_amdgcn_mfma_f32_16x16x32_bf16(
                    *(const short8v*)(ap + f*32), bfr[f], acc, 0,0,0);
            #pragma unroll
            for (int r = 0; r < 4; ++r)
                projL[wv][half*64 + lch*16 + kg*4 + r][col] = acc[r] + pbias;
        }
    }
    __syncthreads();

    // ---- recurrent-W register fragments (read once from Wbf) ----
    short8v wfrF[8], wfrI[8], wfrO[8], wfrU[8];
    #pragma unroll
    for (int f = 0; f < 8; ++f) {
        const int o = col*KP + f*32 + kg*8;
        wfrF[f] = *(const short8v*)(Wbf + (0*WC)*KP + o);
        wfrI[f] = *(const short8v*)(Wbf + (1*WC)*KP + o);
        wfrO[f] = *(const short8v*)(Wbf + (2*WC)*KP + o);
        wfrU[f] = *(const short8v*)(Wbf + (3*WC)*KP + o);
    }

    // ---- CSR prefix sums + scatter ----
    if (t == 0) {
        int off = 0;
        for (int i = 0; i < SS; ++i) { int v = lcur[i]; loff[i] = off; lcur[i] = off; off += v; }
        loff[SS] = off;
        off = 0;
        for (int l2 = 0; l2 < NLEV; ++l2) { int v = lvcur[l2]; lvoff[l2] = off; lvcur[l2] = off; off += v; }
        lvoff[NLEV] = off;
    }
    __syncthreads();
    if (t < TE) {
        int e = b*TE + t;
        int p = parent_idx[e] - b*SS;
        int pos = atomicAdd(&lcur[p], 1);
        llist[pos] = child_idx[e] - b*SS;
    }
    if (t < SS) {
        int hg = node_height[b*SS + t];
        int pos = atomicAdd(&lvcur[hg], 1);
        lvnodes[pos] = t;
    }
    __syncthreads();

    // ---- bottom-up levels; ONE barrier per level ----
    short* Hst = hstage + wv*16*KP;          // this wave's staging [16][KP]
    const int mH = s_maxH;
    for (int lev = 0; lev <= mH; ++lev) {
        const int s0 = lvoff[lev], s1 = lvoff[lev+1];

        if (lev == 0) {
            // leaves: 4 per wave-iteration (16-lane groups)
            for (int it = 0; s0 + it*16 + wv*4 < s1; ++it) {
                int j2 = s0 + it*16 + wv*4 + kg;
                if (j2 < s1) {
                    int n = lvnodes[j2];
                    float iv = sigm(projL[0][n][col] + biasI[col]);
                    float ov = sigm(projL[2][n][col]);
                    float uv = tanhf(projL[3][n][col]);
                    float cv = iv * uv;
                    float hv = ov * tanhf(cv);
                    cloc[n][col] = cv; hloc[n][col] = hv;
                    publish4(hv, col, hx + (size_t)(b*SS + n)*64, col0);
                    if (col == 0)
                        st_devb((unsigned char*)flg + (size_t)(b*SS + n)*16 + cgp, 1);
                }
            }
        } else {
            int j = s0 + wv;
            ull u[16]; int chr[4];
            int nOff = 0, nE = 0;
            if (j < s1) {                     // ISSUE(first node)
                int n0 = lvnodes[j]; nOff = loff[n0]; nE = loff[n0+1] - nOff;
                int m0 = min(nE, 16);
                #pragma unroll
                for (int rw = 0; rw < 4; ++rw) {
                    int e = kg + rw*4;
                    chr[rw] = (e < m0) ? llist[nOff + e] : -1;
                    if (chr[rw] >= 0) {
                        const ull* sp = hx + (size_t)(b*SS + chr[rw])*64 + col*4;
                        #pragma unroll
                        for (int q = 0; q < 4; ++q) u[rw*4+q] = ld_dev(sp+q);
                    }
                }
            }
            while (j < s1) {
                const int n = lvnodes[j];
                const int off = nOff, E = nE;
                float hs0=0.f, hs1=0.f, hs2=0.f, hs3=0.f, fpart=0.f;
                for (int fr = 0; fr < E; fr += 16) {
                    const int m = min(16, E - fr);
                    if (fr > 0) {             // issue this frame (rare E>16)
                        #pragma unroll
                        for (int rw = 0; rw < 4; ++rw) {
                            int e = kg + rw*4;
                            chr[rw] = (e < m) ? llist[off + fr + e] : -1;
                            if (chr[rw] >= 0) {
                                const ull* sp = hx + (size_t)(b*SS + chr[rw])*64 + col*4;
                                #pragma unroll
                                for (int q = 0; q < 4; ++q) u[rw*4+q] = ld_dev(sp+q);
                            }
                        }
                    }
                    // commit: sentinel check; slow path = flag-gated retry
                    for (;;) {
                        bool bad = false;
                        #pragma unroll
                        for (int rw = 0; rw < 4; ++rw)
                            if (chr[rw] >= 0) {
                                #pragma unroll
                                for (int q = 0; q < 4; ++q)
                                    bad = bad || (u[rw*4+q] == SENT64);
                            }
                        if (!bad) break;
                        // cheap flag poll (16B per child, coalesced)
                        bool fready = true;
                        #pragma unroll
                        for (int rw = 0; rw < 4; ++rw)
                            if (chr[rw] >= 0) {
                                const ull* fp = flg + (size_t)(b*SS + chr[rw])*2;
                                ull f0 = ld_dev(fp), f1 = ld_dev(fp+1);
                                fready = fready && (f0 == FLAGS_ALL) && (f1 == FLAGS_ALL);
                            }
                        if (!fready) { __builtin_amdgcn_s_sleep(2); continue; }
                        // flags complete: reload only sentinel words
                        #pragma unroll
                        for (int rw = 0; rw < 4; ++rw)
                            if (chr[rw] >= 0) {
                                const ull* sp = hx + (size_t)(b*SS + chr[rw])*64 + col*4;
                                #pragma unroll
                                for (int q = 0; q < 4; ++q)
                                    if (u[rw*4+q] == SENT64) u[rw*4+q] = ld_dev(sp+q);
                            }
                    }
                    // stage into LDS
                    #pragma unroll
                    for (int rw = 0; rw < 4; ++rw)
                        if (chr[rw] >= 0) {
                            int e = kg + rw*4;
                            ull* dp = (ull*)&Hst[e*KP + col*16];
                            dp[0]=u[rw*4]; dp[1]=u[rw*4+1]; dp[2]=u[rw*4+2]; dp[3]=u[rw*4+3];
                        }
                    // f-MFMA over frame edges
                    f32x4 fa = {0.f,0.f,0.f,0.f};
                    {
                        const int ro = col*KP + kg*8;
                        #pragma unroll
                        for (int f = 0; f < 8; ++f)
                            fa = __builtin_amdgcn_mfma_f32_16x16x32_bf16(
                                *(const short8v*)(Hst + ro + f*32), wfrF[f], fa, 0,0,0);
                    }
                    // fc partial (D row = kg*4+r = frame edge)
                    #pragma unroll
                    for (int r = 0; r < 4; ++r) {
                        int e = kg*4 + r;
                        if (e < m) {
                            int ch2 = llist[off + fr + e];
                            float fg = sigm(fa[r] + biasF[col] + projL[1][n][col]);
                            fpart += fg * cloc[ch2][col];
                        }
                    }
                    // hsum accumulate: lane sums its 4 cols over frame edges
                    for (int e = 0; e < m; ++e) {
                        union { short s[4]; ull v; } rv;
                        rv.v = *(const ull*)&Hst[e*KP + lane*4];
                        hs0 += bf2f(rv.s[0]); hs1 += bf2f(rv.s[1]);
                        hs2 += bf2f(rv.s[2]); hs3 += bf2f(rv.s[3]);
                    }
                }
                // prefetch next node's child rows (hide poll flight under iou)
                int jn = j + 4;
                if (jn < s1) {
                    int n1 = lvnodes[jn]; nOff = loff[n1]; nE = loff[n1+1] - nOff;
                    int m1 = min(nE, 16);
                    #pragma unroll
                    for (int rw = 0; rw < 4; ++rw) {
                        int e = kg + rw*4;
                        chr[rw] = (e < m1) ? llist[nOff + e] : -1;
                        if (chr[rw] >= 0) {
                            const ull* sp = hx + (size_t)(b*SS + chr[rw])*64 + col*4;
                            #pragma unroll
                            for (int q = 0; q < 4; ++q) u[rw*4+q] = ld_dev(sp+q);
                        }
                    }
                }
                // hsum row (bf16) -> iou MFMAs with shared A-frags
                {
                    union { short s[4]; ull v; } hp;
                    hp.s[0]=f2bf(hs0); hp.s[1]=f2bf(hs1);
                    hp.s[2]=f2bf(hs2); hp.s[3]=f2bf(hs3);
                    *(ull*)&hsrow[wv][lane*4] = hp.v;
                }
                f32x4 ia={0.f,0.f,0.f,0.f}, oa={0.f,0.f,0.f,0.f}, ua={0.f,0.f,0.f,0.f};
                {
                    const short* H = &hsrow[wv][0];
                    #pragma unroll
                    for (int f = 0; f < 8; ++f) {
                        short8v af = *(const short8v*)(H + f*32 + kg*8);
                        ia = __builtin_amdgcn_mfma_f32_16x16x32_bf16(af, wfrI[f], ia, 0,0,0);
                        oa = __builtin_amdgcn_mfma_f32_16x16x32_bf16(af, wfrO[f], oa, 0,0,0);
                        ua = __builtin_amdgcn_mfma_f32_16x16x32_bf16(af, wfrU[f], ua, 0,0,0);
                    }
                }
                fpart += __shfl_xor(fpart, 16);
                fpart += __shfl_xor(fpart, 32);
                if (lane < 16) {
                    float iv = sigm(projL[0][n][lane] + ia[0] + biasI[lane]);
                    float ov = sigm(projL[2][n][lane] + oa[0]);
                    float uv = tanhf(projL[3][n][lane] + ua[0]);
                    float cv = iv*uv + fpart;
                    float hv = ov * tanhf(cv);
                    cloc[n][lane] = cv; hloc[n][lane] = hv;
                    publish4(hv, lane, hx + (size_t)(b*SS + n)*64, col0);
                }
                if (lane == 0)
                    st_devb((unsigned char*)flg + (size_t)(b*SS + n)*16 + cgp, 1);
                j = jn;
            }
        }
        barrier_lds();   // cloc/hloc visibility for next level
    }

    // ---- max-pool own columns, exchange via sentinel poolbuf ----
    {
        float* pp = (float*)hstage;          // [16][17] scratch (recurrence done)
        float mx = -3.4e38f;
        for (int s2 = rr; s2 < SS; s2 += RB)
            mx = fmaxf(mx, hloc[s2][cc]);
        pp[rr*17 + cc] = mx;
        __syncthreads();
        if (t < WC) {
            float m2 = pp[0*17 + t];
            #pragma unroll
            for (int r2 = 1; r2 < RB; ++r2) m2 = fmaxf(m2, pp[r2*17 + t]);
            st_devf(&poolbuf[b*HH + col0 + t], m2);
        }
    }
    if (cgp == 0) {
        const int* pb = (const int*)poolbuf + b*HH + t;
        int w = ld_devi(pb);
        while (w == -1) { __builtin_amdgcn_s_sleep(2); w = ld_devi(pb); }
        float* pl = (float*)&hsrow[0][0];    // 256 floats
        pl[t] = __int_as_float(w);
        __syncthreads();
        if (t < LOUT) {
            float acc = b_out[t];
            for (int k = 0; k < HH; ++k)
                acc += pl[k] * W_out[k*LOUT + t];
            out[b*LOUT + t] = acc;
        }
    }
}

// ---------------------------------------------------------------------------
extern "C" void kernel_launch(void* const* d_in, const int* in_sizes, int n_in,
                              void* d_out, int out_size, void* d_ws, size_t ws_size,
                              hipStream_t stream)
{
    const int* xs          = (const int*)d_in[0];
    const int* rels        = (const int*)d_in[1];
    const int* child_idx   = (const int*)d_in[2];
    const int* parent_idx  = (const int*)d_in[3];
    const int* node_height = (const int*)d_in[4];
    // d_in[5] = n_levels (hardcoded NLEV)
    const float* emb_W = (const float*)d_in[6];
    const float* rel_W = (const float*)d_in[7];
    const float* W_ix  = (const float*)d_in[8];
    const float* b_ix  = (const float*)d_in[9];
    const float* W_ih  = (const float*)d_in[10];
    const float* b_ih  = (const float*)d_in[11];
    const float* W_fx  = (const float*)d_in[12];
    const float* b_fx  = (const float*)d_in[13];
    const float* W_fh  = (const float*)d_in[14];
    const float* b_fh  = (const float*)d_in[15];
    const float* W_ox  = (const float*)d_in[16];
    const float* W_oh  = (const float*)d_in[17];
    const float* W_ux  = (const float*)d_in[18];
    const float* W_uh  = (const float*)d_in[19];
    const float* W_out = (const float*)d_in[20];
    const float* b_out = (const float*)d_in[21];

    ull*   hx      = (ull*)d_ws;                               // NN*64 ull = 1 MB
    ull*   flg     = (ull*)((char*)d_ws + (size_t)NN*64*8);    // NN*16 B = 32 KB
    float* poolbuf = (float*)((char*)flg + (size_t)NN*16);     // BB*HH floats

    fill_k<<<256, 256, 0, stream>>>(hx, flg, (int*)poolbuf);

    const unsigned int shmem = (unsigned int)(8u * WC * KP * 2);   // 67584 B
    tree_k<<<dim3(NT*CB), dim3(256), shmem, stream>>>(
        xs, rels, emb_W, rel_W,
        W_ix, b_ix, W_fx, b_fx, W_ox, W_ux,
        child_idx, parent_idx, node_height,
        W_ih, b_ih, W_fh, b_fh, W_oh, W_uh,
        hx, flg, poolbuf,
        W_out, b_out, (float*)d_out);
}

// Round 8
// 205.435 us; speedup vs baseline: 1.1852x; 1.1373x over previous
//
#include <hip/hip_runtime.h>
#include <hip/hip_bf16.h>

// Problem constants (from reference)
#define NN   2048      // B*S nodes
#define BB   16
#define SS   128
#define HH   256       // hidden
#define DE   192
#define DR   64
#define DIN  256
#define LOUT 12
#define NLEV 21
#define TE   127       // edges per tree (S-1)

#define NT   16        // trees
#define CB   16        // col-blocks per tree
#define WC   16        // columns per block
#define NW   8         // waves per block (512 threads)
#define FR   8         // staging frame rows per wave
#define KP   264       // padded bf16 row stride (528B rows, 16B-aligned)

// Sentinel: published h is finite => 4x bf16 NaN(0xFFFF) pattern is impossible.
#define SENT64 0xFFFFFFFFFFFFFFFFULL

typedef unsigned long long ull;
typedef __attribute__((ext_vector_type(8))) short short8v;  // bf16x8 MFMA frag
typedef __attribute__((ext_vector_type(4))) float f32x4;    // MFMA accumulator

__device__ __forceinline__ float sigm(float x){ return 1.f/(1.f + __expf(-x)); }

__device__ __forceinline__ short f2bf(float f){
    union { __hip_bfloat16 b; short s; } v; v.b = __float2bfloat16(f); return v.s;
}
__device__ __forceinline__ float bf2f(short s){
    union { unsigned u; float f; } v; v.u = ((unsigned)(unsigned short)s) << 16; return v.f;
}
// relaxed agent-scope (device-coherent, cache-bypassing) accessors
__device__ __forceinline__ void st_dev(ull* p, ull v){
    __hip_atomic_store(p, v, __ATOMIC_RELAXED, __HIP_MEMORY_SCOPE_AGENT);
}
__device__ __forceinline__ ull ld_dev(const ull* p){
    return __hip_atomic_load(p, __ATOMIC_RELAXED, __HIP_MEMORY_SCOPE_AGENT);
}
__device__ __forceinline__ void st_devf(float* p, float v){
    __hip_atomic_store(p, v, __ATOMIC_RELAXED, __HIP_MEMORY_SCOPE_AGENT);
}
__device__ __forceinline__ int ld_devi(const int* p){
    return __hip_atomic_load(p, __ATOMIC_RELAXED, __HIP_MEMORY_SCOPE_AGENT);
}

// LDS-only barrier: waits DS ops but NOT in-flight global publish stores.
__device__ __forceinline__ void barrier_lds(){
    __builtin_amdgcn_sched_barrier(0);
    asm volatile("s_waitcnt lgkmcnt(0)" ::: "memory");
    __builtin_amdgcn_s_barrier();
    __builtin_amdgcn_sched_barrier(0);
}

// Pack 4 cols (bf16) from 4 adjacent lanes, store 1 ull (lanes with cc%4==0).
__device__ __forceinline__ void publish4(float hv, int cc, ull* rowp, int col0){
    unsigned p = (unsigned short)f2bf(hv);
    unsigned q = (unsigned)__shfl_xor((int)p, 1);
    unsigned pr = p | (q << 16);
    unsigned pr2 = (unsigned)__shfl_xor((int)pr, 2);
    if ((cc & 3) == 0)
        st_dev(rowp + ((col0 + cc) >> 2), pr | ((ull)pr2 << 32));
}

// Issue sentinel-poll loads for queue position jj (first frame, up to FR kids)
#define ISSUE_NODE(jj)                                                     \
    if ((jj) < SS) {                                                       \
        int n1_ = lvnodes[jj]; nOff = loff[n1_]; nE = loff[n1_+1] - nOff;  \
        int m1_ = min(nE, FR);                                             \
        _Pragma("unroll")                                                  \
        for (int rw = 0; rw < 2; ++rw) {                                   \
            int e_ = kg + rw*4;                                            \
            chr[rw] = (e_ < m1_) ? llist[nOff + e_] : -1;                  \
            if (chr[rw] >= 0) {                                            \
                const ull* sp_ = hx + (size_t)(b*SS + chr[rw])*64 + col*4; \
                _Pragma("unroll")                                          \
                for (int q_ = 0; q_ < 4; ++q_) u[rw*4+q_] = ld_dev(sp_+q_);\
            }                                                              \
        }                                                                  \
    }

// ---------------------------------------------------------------------------
// Sentinel pre-fill (race-free: stream-ordered before tree_k)
// ---------------------------------------------------------------------------
__global__ __launch_bounds__(256) void fill_k(ull* __restrict__ hx,
                                              int* __restrict__ pb)
{
    const int t = threadIdx.x;
    const size_t base = (size_t)blockIdx.x * 512 + t;
    st_dev(&hx[base], SENT64);
    st_dev(&hx[base + 256], SENT64);
    if (blockIdx.x == 0) {
        #pragma unroll
        for (int q = 0; q < (BB*HH)/256; ++q)
            __hip_atomic_store(&pb[q*256 + t], -1, __ATOMIC_RELAXED,
                               __HIP_MEMORY_SCOPE_AGENT);
    }
}

// ---------------------------------------------------------------------------
// Wave-autonomous fence-free dataflow recurrence, 8 waves/block.
// 256 blocks = 16 trees x 16 col-blocks, 1 block/CU (2 waves/SIMD).
// Unified height-sorted node queue; wave w owns positions == w (mod 8).
// One barrier per level; next-level polls are issued BEFORE the barrier.
// ---------------------------------------------------------------------------
__global__ __launch_bounds__(512, 1) void tree_k(
    const int* __restrict__ xs, const int* __restrict__ rels,
    const float* __restrict__ emb_W, const float* __restrict__ rel_W,
    const float* __restrict__ W_ix, const float* __restrict__ b_ix,
    const float* __restrict__ W_fx, const float* __restrict__ b_fx,
    const float* __restrict__ W_ox, const float* __restrict__ W_ux,
    const int* __restrict__ child_idx, const int* __restrict__ parent_idx,
    const int* __restrict__ node_height,
    const float* __restrict__ W_ih, const float* __restrict__ b_ih,
    const float* __restrict__ W_fh, const float* __restrict__ b_fh,
    const float* __restrict__ W_oh, const float* __restrict__ W_uh,
    ull* __restrict__ hx, float* __restrict__ poolbuf,
    const float* __restrict__ W_out, const float* __restrict__ b_out,
    float* __restrict__ out)
{
    // ---- dynamic LDS (67584 B) ----
    extern __shared__ __align__(16) char trans[];
    short* Wbf    = (short*)trans;                  // [4][WC][KP] recurrent W, col-major
    short* hstage = (short*)(trans + 4*WC*KP*2);    // [NW waves][FR rows][KP]; prologue xbf [64][KP]

    // ---- static LDS (~57 KB) ----
    __shared__ float projL[4][SS][WC];       // {ix,fx,ox,ux} own-col slices
    __shared__ float cloc[SS][WC+1];
    __shared__ float hloc[SS][WC+1];
    __shared__ short hsrow[NW][KP];          // per-wave hsum row (bf16)
    __shared__ float biasF[WC], biasI[WC];
    __shared__ int loff[SS+1], lcur[SS], llist[SS];
    __shared__ int lvoff[NLEV+1], lvcur[NLEV], lvnodes[SS];
    __shared__ int s_maxH;

    const int t    = threadIdx.x;
    const int bid  = blockIdx.x;
    const int xcd  = bid & 7;                // XCD-affine (perf only)
    const int idx  = bid >> 3;
    const int b    = xcd + 8 * (idx >> 4);   // tree
    const int cgp  = idx & 15;               // col group
    const int col0 = cgp * WC;
    const int cc   = t & 15;
    const int wv   = t >> 6;                 // wave id 0..7
    const int lane = t & 63;
    const int col  = lane & 15;              // MFMA col / output col index
    const int kg   = lane >> 4;              // MFMA k-slot group 0..3
    const int gate = wv & 3;                 // prologue gate
    const int ghalf= wv >> 2;                // prologue row-half

    // ---- P0: stage xs/rels ints; zero counters ----
    if (t < SS) { llist[t] = xs[b*SS + t]; lvnodes[t] = rels[b*SS + t]; lcur[t] = 0; }
    if (t < NLEV) lvcur[t] = 0;
    if (t == 0)   s_maxH = 0;
    __syncthreads();

    // ---- CSR degree atomics + recurrent-W LDS staging + biases + W_x frags ----
    if (t < TE) { int p = parent_idx[b*TE + t] - b*SS; atomicAdd(&lcur[p], 1); }
    if (t < SS) { int hg = node_height[b*SS + t]; atomicAdd(&lvcur[hg], 1); atomicMax(&s_maxH, hg); }
    {
        const float* Wm4[4] = { W_fh, W_ih, W_oh, W_uh };
        const int ccw = t & 15, rrw = (t >> 4) & 15;
        const int mm0 = (t >> 8) * 2;        // threads 0-255: mats 0,1; 256-511: 2,3
        for (int m = mm0; m < mm0 + 2; ++m) {
            short* dst = Wbf + (m*WC + ccw)*KP;
            const float* src = Wm4[m] + col0 + ccw;
            #pragma unroll 4
            for (int kb = 0; kb < 16; ++kb) {
                int k = kb*16 + rrw;
                dst[k] = f2bf(src[(long long)k*HH]);
            }
        }
        if (t < WC) { biasF[t] = b_fh[col0+t]; biasI[t] = b_ih[col0+t]; }
    }
    // W_x B-frags in registers (wave pair {gate, gate+4} loads same gate)
    short8v bfr[8];
    {
        const float* Wxm = (gate==0) ? W_ix : (gate==1) ? W_fx : (gate==2) ? W_ox : W_ux;
        #pragma unroll
        for (int f = 0; f < 8; ++f) {
            #pragma unroll
            for (int j = 0; j < 8; ++j)
                bfr[f][j] = f2bf(Wxm[(long long)(f*32 + kg*8 + j)*HH + col0 + col]);
        }
    }
    const float pbias = (gate==0) ? b_ix[col0+col] : (gate==1) ? b_fx[col0+col] : 0.f;

    // ---- x-gather + proj MFMA in two 64-row halves (xbf overlays hstage) ----
    short* xbf = hstage;   // [64][KP]
    for (int half = 0; half < 2; ++half) {
        __syncthreads();
        #pragma unroll
        for (int r2 = 0; r2 < 8; ++r2) {
            int gr = half*64 + wv*8 + r2;      // global node row
            float4 v;
            if (lane < 48) v = *(const float4*)&emb_W[(long long)llist[gr]*DE + lane*4];
            else           v = *(const float4*)&rel_W[(long long)lvnodes[gr]*DR + (lane-48)*4];
            union { short s[4]; ull u; } pk;
            pk.s[0] = f2bf(v.x); pk.s[1] = f2bf(v.y);
            pk.s[2] = f2bf(v.z); pk.s[3] = f2bf(v.w);
            *(ull*)&xbf[(wv*8 + r2)*KP + lane*4] = pk.u;
        }
        __syncthreads();
        #pragma unroll
        for (int lt = 0; lt < 2; ++lt) {
            int tile = ghalf*2 + lt;           // 0..3 within the half
            f32x4 acc = {0.f,0.f,0.f,0.f};
            const short* ap = xbf + (tile*16 + col)*KP + kg*8;
            #pragma unroll
            for (int f = 0; f < 8; ++f)
                acc = __builtin_amdgcn_mfma_f32_16x16x32_bf16(
                    *(const short8v*)(ap + f*32), bfr[f], acc, 0,0,0);
            #pragma unroll
            for (int r = 0; r < 4; ++r)
                projL[gate][half*64 + tile*16 + kg*4 + r][col] = acc[r] + pbias;
        }
    }
    __syncthreads();

    // ---- recurrent-W register fragments (read once from Wbf) ----
    short8v wfrF[8], wfrI[8], wfrO[8], wfrU[8];
    #pragma unroll
    for (int f = 0; f < 8; ++f) {
        const int o = col*KP + f*32 + kg*8;
        wfrF[f] = *(const short8v*)(Wbf + (0*WC)*KP + o);
        wfrI[f] = *(const short8v*)(Wbf + (1*WC)*KP + o);
        wfrO[f] = *(const short8v*)(Wbf + (2*WC)*KP + o);
        wfrU[f] = *(const short8v*)(Wbf + (3*WC)*KP + o);
    }

    // ---- CSR prefix sums + scatter ----
    if (t == 0) {
        int off = 0;
        for (int i = 0; i < SS; ++i) { int v = lcur[i]; loff[i] = off; lcur[i] = off; off += v; }
        loff[SS] = off;
        off = 0;
        for (int l2 = 0; l2 < NLEV; ++l2) { int v = lvcur[l2]; lvoff[l2] = off; lvcur[l2] = off; off += v; }
        lvoff[NLEV] = off;
    }
    __syncthreads();
    if (t < TE) {
        int e = b*TE + t;
        int p = parent_idx[e] - b*SS;
        int pos = atomicAdd(&lcur[p], 1);
        llist[pos] = child_idx[e] - b*SS;
    }
    if (t < SS) {
        int hg = node_height[b*SS + t];
        int pos = atomicAdd(&lvcur[hg], 1);
        lvnodes[pos] = t;
    }
    __syncthreads();

    // ---- level 0 (leaves): 4 per wave-iteration via kg groups ----
    const int mH = s_maxH;
    {
        const int s0 = lvoff[0], s1 = lvoff[1];
        for (int it = 0; s0 + it*(NW*4) + wv*4 < s1; ++it) {
            int j2 = s0 + it*(NW*4) + wv*4 + kg;
            if (j2 < s1) {
                int n = lvnodes[j2];
                float iv = sigm(projL[0][n][col] + biasI[col]);
                float ov = sigm(projL[2][n][col]);
                float uv = tanhf(projL[3][n][col]);
                float cv = iv * uv;
                float hv = ov * tanhf(cv);
                cloc[n][col] = cv; hloc[n][col] = hv;
                publish4(hv, col, hx + (size_t)(b*SS + n)*64, col0);
            }
        }
    }

    // ---- levels 1..mH: unified queue, prefetch crosses the barrier ----
    short* Hst = hstage + wv*FR*KP;          // this wave's staging [FR][KP]
    {
        int j = lvoff[1] + wv;
        ull u[8]; int chr[2];
        int nOff = 0, nE = 0;
        ISSUE_NODE(j);                       // issued BEFORE the level-0 barrier
        barrier_lds();

        for (int lev = 1; lev <= mH; ++lev) {
            const int s1 = lvoff[lev+1];
            while (j < s1) {
                const int n = lvnodes[j];
                const int off = nOff, E = nE;
                float hs0=0.f, hs1=0.f, hs2=0.f, hs3=0.f, fpart=0.f;

                for (int fr = 0; fr < E; fr += FR) {
                    const int m = min(FR, E - fr);
                    if (fr > 0) {            // rare E>8: issue this frame
                        #pragma unroll
                        for (int rw = 0; rw < 2; ++rw) {
                            int e = kg + rw*4;
                            chr[rw] = (e < m) ? llist[off + fr + e] : -1;
                            if (chr[rw] >= 0) {
                                const ull* sp = hx + (size_t)(b*SS + chr[rw])*64 + col*4;
                                #pragma unroll
                                for (int q = 0; q < 4; ++q) u[rw*4+q] = ld_dev(sp+q);
                            }
                        }
                    }
                    // commit: poll sentinels (reload only missing words)
                    for (;;) {
                        bool bad = false;
                        #pragma unroll
                        for (int rw = 0; rw < 2; ++rw)
                            if (chr[rw] >= 0) {
                                #pragma unroll
                                for (int q = 0; q < 4; ++q)
                                    bad = bad || (u[rw*4+q] == SENT64);
                            }
                        if (!bad) break;
                        __builtin_amdgcn_s_sleep(1);
                        #pragma unroll
                        for (int rw = 0; rw < 2; ++rw)
                            if (chr[rw] >= 0) {
                                const ull* sp = hx + (size_t)(b*SS + chr[rw])*64 + col*4;
                                #pragma unroll
                                for (int q = 0; q < 4; ++q)
                                    if (u[rw*4+q] == SENT64) u[rw*4+q] = ld_dev(sp+q);
                            }
                    }
                    // stage into LDS
                    #pragma unroll
                    for (int rw = 0; rw < 2; ++rw)
                        if (chr[rw] >= 0) {
                            int e = kg + rw*4;
                            ull* dp = (ull*)&Hst[e*KP + col*16];
                            dp[0]=u[rw*4]; dp[1]=u[rw*4+1]; dp[2]=u[rw*4+2]; dp[3]=u[rw*4+3];
                        }
                    // f-MFMA over frame edges (A rows 8-15 clamp-read rows 0-7;
                    // D is row-separable so junk rows >= m are simply unused)
                    f32x4 fa = {0.f,0.f,0.f,0.f};
                    {
                        const int ro = (col & 7)*KP + kg*8;
                        #pragma unroll
                        for (int f = 0; f < 8; ++f)
                            fa = __builtin_amdgcn_mfma_f32_16x16x32_bf16(
                                *(const short8v*)(Hst + ro + f*32), wfrF[f], fa, 0,0,0);
                    }
                    // fc partial (D row = kg*4+r = frame edge; only kg<2 hit m<=8)
                    #pragma unroll
                    for (int r = 0; r < 4; ++r) {
                        int e = kg*4 + r;
                        if (e < m) {
                            int ch2 = llist[off + fr + e];
                            float fg = sigm(fa[r] + biasF[col] + projL[1][n][col]);
                            fpart += fg * cloc[ch2][col];
                        }
                    }
                    // hsum accumulate: lane sums its 4 cols over frame edges
                    for (int e = 0; e < m; ++e) {
                        union { short s[4]; ull v; } rv;
                        rv.v = *(const ull*)&Hst[e*KP + lane*4];
                        hs0 += bf2f(rv.s[0]); hs1 += bf2f(rv.s[1]);
                        hs2 += bf2f(rv.s[2]); hs3 += bf2f(rv.s[3]);
                    }
                }

                // prefetch next assigned node (may be next level: crosses barrier)
                int jn = j + NW;
                ISSUE_NODE(jn);

                // hsum row (bf16) -> iou MFMAs with shared A-frags
                {
                    union { short s[4]; ull v; } hp;
                    hp.s[0]=f2bf(hs0); hp.s[1]=f2bf(hs1);
                    hp.s[2]=f2bf(hs2); hp.s[3]=f2bf(hs3);
                    *(ull*)&hsrow[wv][lane*4] = hp.v;
                }
                f32x4 ia={0.f,0.f,0.f,0.f}, oa={0.f,0.f,0.f,0.f}, ua={0.f,0.f,0.f,0.f};
                {
                    const short* H = &hsrow[wv][0];
                    #pragma unroll
                    for (int f = 0; f < 8; ++f) {
                        short8v af = *(const short8v*)(H + f*32 + kg*8);
                        ia = __builtin_amdgcn_mfma_f32_16x16x32_bf16(af, wfrI[f], ia, 0,0,0);
                        oa = __builtin_amdgcn_mfma_f32_16x16x32_bf16(af, wfrO[f], oa, 0,0,0);
                        ua = __builtin_amdgcn_mfma_f32_16x16x32_bf16(af, wfrU[f], ua, 0,0,0);
                    }
                }
                fpart += __shfl_xor(fpart, 16);
                fpart += __shfl_xor(fpart, 32);
                if (lane < 16) {
                    float iv = sigm(projL[0][n][lane] + ia[0] + biasI[lane]);
                    float ov = sigm(projL[2][n][lane] + oa[0]);
                    float uv = tanhf(projL[3][n][lane] + ua[0]);
                    float cv = iv*uv + fpart;
                    float hv = ov * tanhf(cv);
                    cloc[n][lane] = cv; hloc[n][lane] = hv;
                    publish4(hv, lane, hx + (size_t)(b*SS + n)*64, col0);
                }
                j = jn;
            }
            barrier_lds();   // cloc/hloc visibility for next level
        }
    }

    // ---- max-pool own columns, exchange via sentinel poolbuf ----
    {
        float* pp = (float*)hstage;          // [32][17] scratch (recurrence done)
        const int rp = t >> 4;               // 0..31
        float mx = -3.4e38f;
        for (int s2 = rp; s2 < SS; s2 += 32)
            mx = fmaxf(mx, hloc[s2][cc]);
        pp[rp*17 + cc] = mx;
        __syncthreads();
        if (t < WC) {
            float m2 = pp[0*17 + t];
            #pragma unroll
            for (int r2 = 1; r2 < 32; ++r2) m2 = fmaxf(m2, pp[r2*17 + t]);
            st_devf(&poolbuf[b*HH + col0 + t], m2);
        }
    }
    if (cgp == 0) {
        float* pl = (float*)&hsrow[0][0];    // 256 floats
        if (t < HH) {
            const int* pb = (const int*)poolbuf + b*HH + t;
            int w = ld_devi(pb);
            while (w == -1) { __builtin_amdgcn_s_sleep(1); w = ld_devi(pb); }
            pl[t] = __int_as_float(w);
        }
        __syncthreads();
        if (t < LOUT) {
            float acc = b_out[t];
            for (int k = 0; k < HH; ++k)
                acc += pl[k] * W_out[k*LOUT + t];
            out[b*LOUT + t] = acc;
        }
    }
}

// ---------------------------------------------------------------------------
extern "C" void kernel_launch(void* const* d_in, const int* in_sizes, int n_in,
                              void* d_out, int out_size, void* d_ws, size_t ws_size,
                              hipStream_t stream)
{
    const int* xs          = (const int*)d_in[0];
    const int* rels        = (const int*)d_in[1];
    const int* child_idx   = (const int*)d_in[2];
    const int* parent_idx  = (const int*)d_in[3];
    const int* node_height = (const int*)d_in[4];
    // d_in[5] = n_levels (hardcoded NLEV)
    const float* emb_W = (const float*)d_in[6];
    const float* rel_W = (const float*)d_in[7];
    const float* W_ix  = (const float*)d_in[8];
    const float* b_ix  = (const float*)d_in[9];
    const float* W_ih  = (const float*)d_in[10];
    const float* b_ih  = (const float*)d_in[11];
    const float* W_fx  = (const float*)d_in[12];
    const float* b_fx  = (const float*)d_in[13];
    const float* W_fh  = (const float*)d_in[14];
    const float* b_fh  = (const float*)d_in[15];
    const float* W_ox  = (const float*)d_in[16];
    const float* W_oh  = (const float*)d_in[17];
    const float* W_ux  = (const float*)d_in[18];
    const float* W_uh  = (const float*)d_in[19];
    const float* W_out = (const float*)d_in[20];
    const float* b_out = (const float*)d_in[21];

    ull*   hx      = (ull*)d_ws;                              // NN*64 ull = 1 MB
    float* poolbuf = (float*)((char*)d_ws + (size_t)NN*64*8); // BB*HH floats

    fill_k<<<256, 256, 0, stream>>>(hx, (int*)poolbuf);

    const unsigned int shmem = (unsigned int)((4*WC + NW*FR) * KP * 2);  // 67584 B
    tree_k<<<dim3(NT*CB), dim3(512), shmem, stream>>>(
        xs, rels, emb_W, rel_W,
        W_ix, b_ix, W_fx, b_fx, W_ox, W_ux,
        child_idx, parent_idx, node_height,
        W_ih, b_ih, W_fh, b_fh, W_oh, W_uh,
        hx, poolbuf,
        W_out, b_out, (float*)d_out);
}